// Round 4
// baseline (120.635 us; speedup 1.0000x reference)
//
#include <hip/hip_runtime.h>

typedef __attribute__((ext_vector_type(8))) _Float16 f16x8;
typedef __attribute__((ext_vector_type(4))) _Float16 f16x4;
typedef __attribute__((ext_vector_type(4))) float f32x4;

#define BHn 64
#define Nn 1024

static constexpr int kOutMvElems = 8 * 8 * 1024 * 128;      // 8388608
static constexpr float kScaleLog2e = 0.11405506f;           // log2(e)/sqrt(160)
static constexpr unsigned kNegMask = 0xBF1Cu;               // BLADE_METRIC<0 bit i

// ---------------- pack K: f32 (mv|s) -> f16 [bh][key][160] ----------------
__global__ __launch_bounds__(256) void pack_k_kernel(const float* __restrict__ kmv,
                                                     const float* __restrict__ ks,
                                                     _Float16* __restrict__ Kf) {
  int t = blockIdx.x * 256 + threadIdx.x;  // 16B segment id
  const int total = BHn * Nn * 20;
  if (t >= total) return;
  int row = t / 20, s = t - row * 20;
  const float* src = (s < 16) ? (kmv + (size_t)row * 128 + s * 8)
                              : (ks + (size_t)row * 32 + (s - 16) * 8);
  float4 a = *(const float4*)src;
  float4 b = *(const float4*)(src + 4);
  f16x8 h;
  h[0] = (_Float16)a.x; h[1] = (_Float16)a.y; h[2] = (_Float16)a.z; h[3] = (_Float16)a.w;
  h[4] = (_Float16)b.x; h[5] = (_Float16)b.y; h[6] = (_Float16)b.z; h[7] = (_Float16)b.w;
  *(f16x8*)(Kf + (size_t)row * 160 + s * 8) = h;
}

// ---- pack V transposed + slot-permuted: f32 [bh][key][160] -> f16 [bh][d][1024] ----
// Column order within each 32-key chunk is sigma(slot): slot 8g+i -> key 4g+i (i<4),
// 16+4g+(i-4) (i>=4). This makes the PV A-fragment lane-local (zero-shuffle P).
__global__ __launch_bounds__(256) void pack_vt_kernel(const float* __restrict__ vmv,
                                                      const float* __restrict__ vs,
                                                      _Float16* __restrict__ Vt) {
  __shared__ _Float16 tile[160][72];
  const int bh = blockIdx.y;
  const int kt = blockIdx.x;  // 16 tiles of 64 keys
  const int tid = threadIdx.x;
  for (int s = tid; s < 64 * 40; s += 256) {
    int key = s / 40, p = s - key * 40;
    int row = bh * Nn + kt * 64 + key;
    const float* src = (p < 32) ? (vmv + (size_t)row * 128 + p * 4)
                                : (vs + (size_t)row * 32 + (p - 32) * 4);
    float4 v = *(const float4*)src;
    int d = p * 4;
    tile[d + 0][key] = (_Float16)v.x;
    tile[d + 1][key] = (_Float16)v.y;
    tile[d + 2][key] = (_Float16)v.z;
    tile[d + 3][key] = (_Float16)v.w;
  }
  __syncthreads();
  for (int s = tid; s < 160 * 8; s += 256) {
    int d = s >> 3, o = s & 7;                 // o = output octet within 64 cols
    int c32 = (o >> 2) * 32;                   // 32-key chunk base
    int g4 = (o & 3) * 4;
    f16x4 lo = *(const f16x4*)&tile[d][c32 + g4];        // keys 4g..4g+3
    f16x4 hi = *(const f16x4*)&tile[d][c32 + 16 + g4];   // keys 16+4g..16+4g+3
    f16x8 h;
    h[0] = lo[0]; h[1] = lo[1]; h[2] = lo[2]; h[3] = lo[3];
    h[4] = hi[0]; h[5] = hi[1]; h[6] = hi[2]; h[7] = hi[3];
    *(f16x8*)(Vt + ((size_t)(bh * 160 + d)) * 1024 + kt * 64 + o * 8) = h;
  }
}

// ---------------- flash attention: 4 waves x 32 rows, single-buffer, 2 blocks/CU ----------------
// grid: 512 blocks (XCD-swizzled -> (qb, bh)); 256 threads = 4 waves.
__global__ __launch_bounds__(256, 2) void geo_attn_kernel(const float* __restrict__ qmv,
                                                          const float* __restrict__ qs,
                                                          const _Float16* __restrict__ Kf,
                                                          const _Float16* __restrict__ Vt,
                                                          float* __restrict__ out) {
  __shared__ _Float16 k_lds[64 * 192];    // 64 keys x 160 (stride 192, XOR-swizzled)
  __shared__ _Float16 v_lds[160 * 64];    // 160 d x 64 slots (XOR-swizzled)

  // XCD swizzle: 512 blocks, XCD x gets bh 8x..8x+7 (all 8 q-blocks each)
  const int b = blockIdx.x;
  const int sw = (b & 7) * 64 + (b >> 3);
  const int qb = sw & 7;
  const int bh = sw >> 3;

  const int tid = threadIdx.x;
  const int w = tid >> 6;
  const int l = tid & 63;
  const int g = l >> 4;
  const int nn = l & 15;
  const int swz = (nn & 7) << 3;

  // ---- staging geometry, hoisted (2560 segs, 10/thread: 5 K + 5 V) ----
  int gK[5], lKi[5], gV[5], lVi[5];
#pragma unroll
  for (int i = 0; i < 5; ++i) {
    int sk = tid + 256 * i;
    int key = sk / 20, p = sk - key * 20;
    gK[i] = key * 160 + p * 8;
    lKi[i] = (key * 192 + p * 8) ^ ((key & 7) << 3);
    int d = sk >> 3, cs = sk & 7;
    gV[i] = d * Nn + cs * 8;
    lVi[i] = (d * 64 + cs * 8) ^ ((d & 7) << 3);
  }

  // ---- Q fragments (B-frag): lane holds Q[q=nn(+16)][c*32+8g+i], metric*log2e/sqrt(d) folded ----
  f16x8 qf[2][5];
#pragma unroll
  for (int q2 = 0; q2 < 2; ++q2) {
    const size_t qbase = (size_t)(bh * Nn + qb * 128 + w * 32 + q2 * 16 + nn);
#pragma unroll
    for (int c = 0; c < 5; ++c) {
      const float* src = (c < 4) ? (qmv + qbase * 128 + c * 32 + 8 * g)
                                 : (qs + qbase * 32 + 8 * g);
      float4 a = *(const float4*)src;
      float4 bb = *(const float4*)(src + 4);
      float x[8] = {a.x, a.y, a.z, a.w, bb.x, bb.y, bb.z, bb.w};
#pragma unroll
      for (int i = 0; i < 8; ++i) {
        float v = x[i] * kScaleLog2e;
        if (c < 4) {
          int idx = ((g & 1) << 3) + i;
          v = ((kNegMask >> idx) & 1u) ? -v : v;
        }
        qf[q2][c][i] = (_Float16)v;
      }
    }
  }

  f32x4 acc[2][10];
#pragma unroll
  for (int q2 = 0; q2 < 2; ++q2)
#pragma unroll
    for (int j = 0; j < 10; ++j) acc[q2][j] = (f32x4){0.f, 0.f, 0.f, 0.f};
  float Ma = -3.0e38f, Mb = -3.0e38f, La = 0.f, Lb = 0.f;  // La/Lb: per-lane partials

  const _Float16* kg = Kf + (size_t)(bh * Nn) * 160;
  const _Float16* vg = Vt + (size_t)bh * 160 * Nn;

  f16x8 st[10];
  // preload + write tile 0
#pragma unroll
  for (int i = 0; i < 5; ++i) st[i] = *(const f16x8*)(kg + gK[i]);
#pragma unroll
  for (int i = 0; i < 5; ++i) st[5 + i] = *(const f16x8*)(vg + gV[i]);
#pragma unroll
  for (int i = 0; i < 5; ++i) *(f16x8*)&k_lds[lKi[i]] = st[i];
#pragma unroll
  for (int i = 0; i < 5; ++i) *(f16x8*)&v_lds[lVi[i]] = st[5 + i];
  __syncthreads();

  for (int it = 0; it < 16; ++it) {
    // T14: issue next tile's loads first; they fly across QK+softmax+PV
    if (it < 15) {
      const int key0 = (it + 1) * 64;
#pragma unroll
      for (int i = 0; i < 5; ++i) st[i] = *(const f16x8*)(kg + (size_t)key0 * 160 + gK[i]);
#pragma unroll
      for (int i = 0; i < 5; ++i) st[5 + i] = *(const f16x8*)(vg + key0 + gV[i]);
    }

    // ---- S^T = K Q^T : lane (g,nn) -> scores of q-row nn, keys 16kb+4g+r ----
    f32x4 sa[4], sb[4];
#pragma unroll
    for (int kb = 0; kb < 4; ++kb) {
      sa[kb] = (f32x4){0.f, 0.f, 0.f, 0.f};
      sb[kb] = (f32x4){0.f, 0.f, 0.f, 0.f};
    }
    __builtin_amdgcn_s_setprio(1);
#pragma unroll
    for (int c = 0; c < 5; ++c) {
      f16x8 kf[4];
#pragma unroll
      for (int kb = 0; kb < 4; ++kb)
        kf[kb] = *(const f16x8*)&k_lds[((16 * kb + nn) * 192 + c * 32 + 8 * g) ^ swz];
#pragma unroll
      for (int kb = 0; kb < 4; ++kb) {
        sa[kb] = __builtin_amdgcn_mfma_f32_16x16x32_f16(kf[kb], qf[0][c], sa[kb], 0, 0, 0);
        sb[kb] = __builtin_amdgcn_mfma_f32_16x16x32_f16(kf[kb], qf[1][c], sb[kb], 0, 0, 0);
      }
    }
    __builtin_amdgcn_s_setprio(0);

    // ---- softmax: shuffle-free common path (per-lane defer check) ----
    float lma = fmaxf(fmaxf(fmaxf(fmaxf(sa[0][0], sa[0][1]), fmaxf(sa[0][2], sa[0][3])),
                            fmaxf(fmaxf(sa[1][0], sa[1][1]), fmaxf(sa[1][2], sa[1][3]))),
                      fmaxf(fmaxf(fmaxf(sa[2][0], sa[2][1]), fmaxf(sa[2][2], sa[2][3])),
                            fmaxf(fmaxf(sa[3][0], sa[3][1]), fmaxf(sa[3][2], sa[3][3]))));
    float lmb = fmaxf(fmaxf(fmaxf(fmaxf(sb[0][0], sb[0][1]), fmaxf(sb[0][2], sb[0][3])),
                            fmaxf(fmaxf(sb[1][0], sb[1][1]), fmaxf(sb[1][2], sb[1][3]))),
                      fmaxf(fmaxf(fmaxf(sb[2][0], sb[2][1]), fmaxf(sb[2][2], sb[2][3])),
                            fmaxf(fmaxf(sb[3][0], sb[3][1]), fmaxf(sb[3][2], sb[3][3]))));
    bool need = (lma - Ma > 8.f) || (lmb - Mb > 8.f);
    if (__any((int)need)) {   // rare: iter 0 + occasional
      float pma = fmaxf(lma, __shfl_xor(lma, 16));
      pma = fmaxf(pma, __shfl_xor(pma, 32));
      float pmb = fmaxf(lmb, __shfl_xor(lmb, 16));
      pmb = fmaxf(pmb, __shfl_xor(pmb, 32));
      float nMa = fmaxf(Ma, pma); float fsa = exp2f(Ma - nMa); Ma = nMa;
      float nMb = fmaxf(Mb, pmb); float fsb = exp2f(Mb - nMb); Mb = nMb;
      La *= fsa; Lb *= fsb;
      float fa[4], fb[4];
#pragma unroll
      for (int r = 0; r < 4; ++r) {
        fa[r] = __shfl(fsa, 4 * g + r, 16);
        fb[r] = __shfl(fsb, 4 * g + r, 16);
      }
#pragma unroll
      for (int j = 0; j < 10; ++j)
#pragma unroll
        for (int r = 0; r < 4; ++r) {
          acc[0][j][r] *= fa[r];
          acc[1][j][r] *= fb[r];
        }
    }

    // ---- P in-register (zero-shuffle, sigma slot order); L as per-lane partial ----
    float rsa = 0.f, rsb = 0.f;
    f16x8 paf[2], pbf[2];
#pragma unroll
    for (int kb = 0; kb < 4; ++kb) {
      const int ch = kb >> 1, off = (kb & 1) * 4;
#pragma unroll
      for (int r = 0; r < 4; ++r) {
        float pa_ = exp2f(sa[kb][r] - Ma);
        float pb_ = exp2f(sb[kb][r] - Mb);
        rsa += pa_; rsb += pb_;
        paf[ch][off + r] = (_Float16)pa_;
        pbf[ch][off + r] = (_Float16)pb_;
      }
    }
    La += rsa;
    Lb += rsb;

    // ---- O += P V (V columns pre-permuted by sigma at pack time) ----
    __builtin_amdgcn_s_setprio(1);
#pragma unroll
    for (int ch = 0; ch < 2; ++ch) {
#pragma unroll
      for (int j = 0; j < 10; ++j) {
        f16x8 vb = *(const f16x8*)&v_lds[((16 * j + nn) * 64 + ch * 32 + 8 * g) ^ swz];
        acc[0][j] = __builtin_amdgcn_mfma_f32_16x16x32_f16(paf[ch], vb, acc[0][j], 0, 0, 0);
        acc[1][j] = __builtin_amdgcn_mfma_f32_16x16x32_f16(pbf[ch], vb, acc[1][j], 0, 0, 0);
      }
    }
    __builtin_amdgcn_s_setprio(0);

    // ---- write next tile (loads have been in flight across the whole compute) ----
    if (it < 15) {
      __syncthreads();   // all waves done reading current tile
#pragma unroll
      for (int i = 0; i < 5; ++i) *(f16x8*)&k_lds[lKi[i]] = st[i];
#pragma unroll
      for (int i = 0; i < 5; ++i) *(f16x8*)&v_lds[lVi[i]] = st[5 + i];
      __syncthreads(); // tile ready
    }
  }

  // ---- epilogue: reduce per-lane L partials, normalize, scatter ----
  La += __shfl_xor(La, 16); La += __shfl_xor(La, 32);
  Lb += __shfl_xor(Lb, 16); Lb += __shfl_xor(Lb, 32);
  float ria = 1.f / La, rib = 1.f / Lb;
  float ra[4], rb_[4];
#pragma unroll
  for (int r = 0; r < 4; ++r) {
    ra[r] = __shfl(ria, 4 * g + r, 16);
    rb_[r] = __shfl(rib, 4 * g + r, 16);
  }
  const int row0 = bh * Nn + qb * 128 + w * 32;
#pragma unroll
  for (int j = 0; j < 10; ++j) {
    const int d = 16 * j + nn;
#pragma unroll
    for (int r = 0; r < 4; ++r) {
      float v0 = acc[0][j][r] * ra[r];
      float v1 = acc[1][j][r] * rb_[r];
      const int r0 = row0 + 4 * g + r;
      const int r1 = row0 + 16 + 4 * g + r;
      if (d < 128) {
        out[(size_t)r0 * 128 + d] = v0;
        out[(size_t)r1 * 128 + d] = v1;
      } else {
        out[(size_t)kOutMvElems + (size_t)r0 * 32 + (d - 128)] = v0;
        out[(size_t)kOutMvElems + (size_t)r1 * 32 + (d - 128)] = v1;
      }
    }
  }
}

extern "C" void kernel_launch(void* const* d_in, const int* in_sizes, int n_in,
                              void* d_out, int out_size, void* d_ws, size_t ws_size,
                              hipStream_t stream) {
  const float* qmv = (const float*)d_in[0];
  const float* kmv = (const float*)d_in[1];
  const float* vmv = (const float*)d_in[2];
  const float* qs = (const float*)d_in[3];
  const float* ks = (const float*)d_in[4];
  const float* vs = (const float*)d_in[5];
  float* out = (float*)d_out;

  _Float16* Kf = (_Float16*)d_ws;                       // 64*1024*160 f16
  _Float16* Vt = Kf + (size_t)BHn * Nn * 160;           // 64*160*1024 f16 (sigma-permuted)

  pack_k_kernel<<<dim3((BHn * Nn * 20) / 256), dim3(256), 0, stream>>>(kmv, ks, Kf);
  pack_vt_kernel<<<dim3(16, BHn), dim3(256), 0, stream>>>(vmv, vs, Vt);
  geo_attn_kernel<<<dim3(512), dim3(256), 0, stream>>>(qmv, qs, Kf, Vt, out);
}

// Round 5
// 83.153 us; speedup vs baseline: 1.4508x; 1.4508x over previous
//
#include <hip/hip_runtime.h>

typedef __attribute__((ext_vector_type(8))) _Float16 f16x8;
typedef __attribute__((ext_vector_type(4))) _Float16 f16x4;
typedef __attribute__((ext_vector_type(4))) float f32x4;

#define BHn 64
#define Nn 1024

static constexpr int kOutMvElems = 8 * 8 * 1024 * 128;      // 8388608
static constexpr float kScaleLog2e = 0.11405506f;           // log2(e)/sqrt(160)
static constexpr unsigned kNegMask = 0xBF1Cu;               // BLADE_METRIC<0 bit i
static constexpr int kVBase = 64 * 192;                     // V offset in combined LDS (f16 elems)
static constexpr int kTileF16 = 64 * 192 + 160 * 64;        // 22528 f16 per buffer

// ---------------- pack K: f32 (mv|s) -> f16 [bh][key][160] ----------------
__global__ __launch_bounds__(256) void pack_k_kernel(const float* __restrict__ kmv,
                                                     const float* __restrict__ ks,
                                                     _Float16* __restrict__ Kf) {
  int t = blockIdx.x * 256 + threadIdx.x;  // 16B segment id
  const int total = BHn * Nn * 20;
  if (t >= total) return;
  int row = t / 20, s = t - row * 20;
  const float* src = (s < 16) ? (kmv + (size_t)row * 128 + s * 8)
                              : (ks + (size_t)row * 32 + (s - 16) * 8);
  float4 a = *(const float4*)src;
  float4 b = *(const float4*)(src + 4);
  f16x8 h;
  h[0] = (_Float16)a.x; h[1] = (_Float16)a.y; h[2] = (_Float16)a.z; h[3] = (_Float16)a.w;
  h[4] = (_Float16)b.x; h[5] = (_Float16)b.y; h[6] = (_Float16)b.z; h[7] = (_Float16)b.w;
  *(f16x8*)(Kf + (size_t)row * 160 + s * 8) = h;
}

// ---- pack V transposed + slot-permuted: f32 [bh][key][160] -> f16 [bh][d][1024] ----
// sigma(slot 8g+i) = 4g+i (i<4), 16+4g+(i-4) (i>=4): PV A-frag becomes lane-local.
__global__ __launch_bounds__(256) void pack_vt_kernel(const float* __restrict__ vmv,
                                                      const float* __restrict__ vs,
                                                      _Float16* __restrict__ Vt) {
  __shared__ _Float16 tile[160][72];
  const int bh = blockIdx.y;
  const int kt = blockIdx.x;  // 16 tiles of 64 keys
  const int tid = threadIdx.x;
  for (int s = tid; s < 64 * 40; s += 256) {
    int key = s / 40, p = s - key * 40;
    int row = bh * Nn + kt * 64 + key;
    const float* src = (p < 32) ? (vmv + (size_t)row * 128 + p * 4)
                                : (vs + (size_t)row * 32 + (p - 32) * 4);
    float4 v = *(const float4*)src;
    int d = p * 4;
    tile[d + 0][key] = (_Float16)v.x;
    tile[d + 1][key] = (_Float16)v.y;
    tile[d + 2][key] = (_Float16)v.z;
    tile[d + 3][key] = (_Float16)v.w;
  }
  __syncthreads();
  for (int s = tid; s < 160 * 8; s += 256) {
    int d = s >> 3, o = s & 7;
    int c32 = (o >> 2) * 32;
    int g4 = (o & 3) * 4;
    f16x4 lo = *(const f16x4*)&tile[d][c32 + g4];
    f16x4 hi = *(const f16x4*)&tile[d][c32 + 16 + g4];
    f16x8 h;
    h[0] = lo[0]; h[1] = lo[1]; h[2] = lo[2]; h[3] = lo[3];
    h[4] = hi[0]; h[5] = hi[1]; h[6] = hi[2]; h[7] = hi[3];
    *(f16x8*)(Vt + ((size_t)(bh * 160 + d)) * 1024 + kt * 64 + o * 8) = h;
  }
}

// ------- flash attention: 8 waves x 32 rows, dbuf LDS, 1 barrier/iter (R3 structure) -------
// grid: 256 blocks (XCD-swizzled -> (qb, bh)); 512 threads = 8 waves.
__global__ __launch_bounds__(512, 2) void geo_attn_kernel(const float* __restrict__ qmv,
                                                          const float* __restrict__ qs,
                                                          const _Float16* __restrict__ Kf,
                                                          const _Float16* __restrict__ Vt,
                                                          float* __restrict__ out) {
  __shared__ _Float16 kv_lds[2][kTileF16];  // [K 64x192 | V 160x64], double-buffered, 88 KB

  // XCD swizzle: 256 blocks, XCD x gets bh 8x..8x+7 (all 4 q-blocks each)
  const int b = blockIdx.x;
  const int sw = (b & 7) * 32 + (b >> 3);
  const int qb = sw & 3;
  const int bh = sw >> 2;

  const int tid = threadIdx.x;
  const int w = tid >> 6;
  const int l = tid & 63;
  const int g = l >> 4;
  const int nn = l & 15;
  const int swz = (nn & 7) << 3;

  const _Float16* kg = Kf + (size_t)(bh * Nn) * 160;
  const _Float16* vg = Vt + (size_t)bh * 160 * Nn;

  // ---- staging geometry, hoisted: 2560 segs, 5/thread; ptr+stride per seg ----
  const _Float16* sp[5];
  int sstp[5], lOff[5];
#pragma unroll
  for (int i = 0; i < 5; ++i) {
    int sk = tid + 512 * i;
    if (sk < 1280) {  // K segment
      int key = sk / 20, p = sk - key * 20;
      sp[i] = kg + key * 160 + p * 8;
      sstp[i] = 64 * 160;
      lOff[i] = (key * 192 + p * 8) ^ ((key & 7) << 3);
    } else {          // V segment
      int s2 = sk - 1280;
      int d = s2 >> 3, cs = s2 & 7;
      sp[i] = vg + d * Nn + cs * 8;
      sstp[i] = 64;
      lOff[i] = kVBase + ((d * 64 + cs * 8) ^ ((d & 7) << 3));
    }
  }

  // ---- hoisted LDS read bases (XOR commutes with +3072*kb / +1024*j) ----
  int kbase[5], vbase[2];
#pragma unroll
  for (int c = 0; c < 5; ++c) kbase[c] = (nn * 192 + c * 32 + 8 * g) ^ swz;
#pragma unroll
  for (int ch = 0; ch < 2; ++ch) vbase[ch] = kVBase + ((nn * 64 + ch * 32 + 8 * g) ^ swz);

  // ---- Q fragments (B-frag): lane holds Q[q=nn(+16)][c*32+8g+i], metric*log2e/sqrt(d) folded ----
  f16x8 qf[2][5];
#pragma unroll
  for (int q2 = 0; q2 < 2; ++q2) {
    const size_t qbase = (size_t)(bh * Nn + qb * 256 + w * 32 + q2 * 16 + nn);
#pragma unroll
    for (int c = 0; c < 5; ++c) {
      const float* src = (c < 4) ? (qmv + qbase * 128 + c * 32 + 8 * g)
                                 : (qs + qbase * 32 + 8 * g);
      float4 a = *(const float4*)src;
      float4 bb = *(const float4*)(src + 4);
      float x[8] = {a.x, a.y, a.z, a.w, bb.x, bb.y, bb.z, bb.w};
#pragma unroll
      for (int i = 0; i < 8; ++i) {
        float v = x[i] * kScaleLog2e;
        if (c < 4) {
          int idx = ((g & 1) << 3) + i;
          v = ((kNegMask >> idx) & 1u) ? -v : v;
        }
        qf[q2][c][i] = (_Float16)v;
      }
    }
  }

  f32x4 acc[2][10];
#pragma unroll
  for (int q2 = 0; q2 < 2; ++q2)
#pragma unroll
    for (int j = 0; j < 10; ++j) acc[q2][j] = (f32x4){0.f, 0.f, 0.f, 0.f};
  float Ma = -3.0e38f, Mb = -3.0e38f, La = 0.f, Lb = 0.f;  // L: per-lane partials

  f16x8 st[5];
  // preload + write tile 0
#pragma unroll
  for (int i = 0; i < 5; ++i) { st[i] = *(const f16x8*)sp[i]; sp[i] += sstp[i]; }
#pragma unroll
  for (int i = 0; i < 5; ++i) *(f16x8*)&kv_lds[0][lOff[i]] = st[i];
  __syncthreads();

  for (int it = 0; it < 16; ++it) {
    const int cur = it & 1;
    // T14: issue next tile's loads first; they fly across QK+softmax+PV
    if (it < 15) {
#pragma unroll
      for (int i = 0; i < 5; ++i) { st[i] = *(const f16x8*)sp[i]; sp[i] += sstp[i]; }
    }

    // ---- S^T = K Q^T : lane (g,nn) -> scores of q-row nn, keys 16kb+4g+r ----
    f32x4 sa[4], sb[4];
#pragma unroll
    for (int kb = 0; kb < 4; ++kb) {
      sa[kb] = (f32x4){0.f, 0.f, 0.f, 0.f};
      sb[kb] = (f32x4){0.f, 0.f, 0.f, 0.f};
    }
    const _Float16* kl = kv_lds[cur];
    __builtin_amdgcn_s_setprio(1);
#pragma unroll
    for (int c = 0; c < 5; ++c) {
      f16x8 kf[4];
#pragma unroll
      for (int kb = 0; kb < 4; ++kb)
        kf[kb] = *(const f16x8*)&kl[kbase[c] + 3072 * kb];
#pragma unroll
      for (int kb = 0; kb < 4; ++kb) {
        sa[kb] = __builtin_amdgcn_mfma_f32_16x16x32_f16(kf[kb], qf[0][c], sa[kb], 0, 0, 0);
        sb[kb] = __builtin_amdgcn_mfma_f32_16x16x32_f16(kf[kb], qf[1][c], sb[kb], 0, 0, 0);
      }
    }
    __builtin_amdgcn_s_setprio(0);

    // ---- softmax: shuffle-free common path (per-lane defer check) ----
    float lma = fmaxf(fmaxf(fmaxf(fmaxf(sa[0][0], sa[0][1]), fmaxf(sa[0][2], sa[0][3])),
                            fmaxf(fmaxf(sa[1][0], sa[1][1]), fmaxf(sa[1][2], sa[1][3]))),
                      fmaxf(fmaxf(fmaxf(sa[2][0], sa[2][1]), fmaxf(sa[2][2], sa[2][3])),
                            fmaxf(fmaxf(sa[3][0], sa[3][1]), fmaxf(sa[3][2], sa[3][3]))));
    float lmb = fmaxf(fmaxf(fmaxf(fmaxf(sb[0][0], sb[0][1]), fmaxf(sb[0][2], sb[0][3])),
                            fmaxf(fmaxf(sb[1][0], sb[1][1]), fmaxf(sb[1][2], sb[1][3]))),
                      fmaxf(fmaxf(fmaxf(sb[2][0], sb[2][1]), fmaxf(sb[2][2], sb[2][3])),
                            fmaxf(fmaxf(sb[3][0], sb[3][1]), fmaxf(sb[3][2], sb[3][3]))));
    bool need = (lma - Ma > 8.f) || (lmb - Mb > 8.f);
    if (__any((int)need)) {   // rare: iter 0 + occasional
      float pma = fmaxf(lma, __shfl_xor(lma, 16));
      pma = fmaxf(pma, __shfl_xor(pma, 32));
      float pmb = fmaxf(lmb, __shfl_xor(lmb, 16));
      pmb = fmaxf(pmb, __shfl_xor(pmb, 32));
      float nMa = fmaxf(Ma, pma); float fsa = exp2f(Ma - nMa); Ma = nMa;
      float nMb = fmaxf(Mb, pmb); float fsb = exp2f(Mb - nMb); Mb = nMb;
      La *= fsa; Lb *= fsb;
      float fa[4], fb[4];
#pragma unroll
      for (int r = 0; r < 4; ++r) {
        fa[r] = __shfl(fsa, 4 * g + r, 16);
        fb[r] = __shfl(fsb, 4 * g + r, 16);
      }
#pragma unroll
      for (int j = 0; j < 10; ++j)
#pragma unroll
        for (int r = 0; r < 4; ++r) {
          acc[0][j][r] *= fa[r];
          acc[1][j][r] *= fb[r];
        }
    }

    // ---- P in-register (zero-shuffle, sigma slot order); L per-lane partial ----
    float rsa = 0.f, rsb = 0.f;
    f16x8 paf[2], pbf[2];
#pragma unroll
    for (int kb = 0; kb < 4; ++kb) {
      const int ch = kb >> 1, off = (kb & 1) * 4;
#pragma unroll
      for (int r = 0; r < 4; ++r) {
        float pa_ = exp2f(sa[kb][r] - Ma);
        float pb_ = exp2f(sb[kb][r] - Mb);
        rsa += pa_; rsb += pb_;
        paf[ch][off + r] = (_Float16)pa_;
        pbf[ch][off + r] = (_Float16)pb_;
      }
    }
    La += rsa;
    Lb += rsb;

    // ---- O += P V (V columns pre-permuted by sigma at pack time) ----
    __builtin_amdgcn_s_setprio(1);
#pragma unroll
    for (int ch = 0; ch < 2; ++ch) {
#pragma unroll
      for (int j = 0; j < 10; ++j) {
        f16x8 vb = *(const f16x8*)&kl[vbase[ch] + 1024 * j];
        acc[0][j] = __builtin_amdgcn_mfma_f32_16x16x32_f16(paf[ch], vb, acc[0][j], 0, 0, 0);
        acc[1][j] = __builtin_amdgcn_mfma_f32_16x16x32_f16(pbf[ch], vb, acc[1][j], 0, 0, 0);
      }
    }
    __builtin_amdgcn_s_setprio(0);

    // write next tile into buf^1 (current-buf readers protected by end barrier)
    if (it < 15) {
      _Float16* wl = kv_lds[cur ^ 1];
#pragma unroll
      for (int i = 0; i < 5; ++i) *(f16x8*)&wl[lOff[i]] = st[i];
    }
    __syncthreads();
  }

  // ---- epilogue: reduce per-lane L partials, normalize, scatter ----
  La += __shfl_xor(La, 16); La += __shfl_xor(La, 32);
  Lb += __shfl_xor(Lb, 16); Lb += __shfl_xor(Lb, 32);
  float ria = 1.f / La, rib = 1.f / Lb;
  float ra[4], rb_[4];
#pragma unroll
  for (int r = 0; r < 4; ++r) {
    ra[r] = __shfl(ria, 4 * g + r, 16);
    rb_[r] = __shfl(rib, 4 * g + r, 16);
  }
  const int row0 = bh * Nn + qb * 256 + w * 32;
#pragma unroll
  for (int j = 0; j < 10; ++j) {
    const int d = 16 * j + nn;
#pragma unroll
    for (int r = 0; r < 4; ++r) {
      float v0 = acc[0][j][r] * ra[r];
      float v1 = acc[1][j][r] * rb_[r];
      const int r0 = row0 + 4 * g + r;
      const int r1 = row0 + 16 + 4 * g + r;
      if (d < 128) {
        out[(size_t)r0 * 128 + d] = v0;
        out[(size_t)r1 * 128 + d] = v1;
      } else {
        out[(size_t)kOutMvElems + (size_t)r0 * 32 + (d - 128)] = v0;
        out[(size_t)kOutMvElems + (size_t)r1 * 32 + (d - 128)] = v1;
      }
    }
  }
}

extern "C" void kernel_launch(void* const* d_in, const int* in_sizes, int n_in,
                              void* d_out, int out_size, void* d_ws, size_t ws_size,
                              hipStream_t stream) {
  const float* qmv = (const float*)d_in[0];
  const float* kmv = (const float*)d_in[1];
  const float* vmv = (const float*)d_in[2];
  const float* qs = (const float*)d_in[3];
  const float* ks = (const float*)d_in[4];
  const float* vs = (const float*)d_in[5];
  float* out = (float*)d_out;

  _Float16* Kf = (_Float16*)d_ws;                       // 64*1024*160 f16
  _Float16* Vt = Kf + (size_t)BHn * Nn * 160;           // 64*160*1024 f16 (sigma-permuted)

  pack_k_kernel<<<dim3((BHn * Nn * 20) / 256), dim3(256), 0, stream>>>(kmv, ks, Kf);
  pack_vt_kernel<<<dim3(16, BHn), dim3(256), 0, stream>>>(vmv, vs, Vt);
  geo_attn_kernel<<<dim3(256), dim3(512), 0, stream>>>(qmv, qs, Kf, Vt, out);
}

// Round 6
// 81.614 us; speedup vs baseline: 1.4781x; 1.0189x over previous
//
#include <hip/hip_runtime.h>

typedef __attribute__((ext_vector_type(8))) _Float16 f16x8;
typedef __attribute__((ext_vector_type(4))) _Float16 f16x4;
typedef __attribute__((ext_vector_type(4))) float f32x4;

#define BHn 64
#define Nn 1024

static constexpr int kOutMvElems = 8 * 8 * 1024 * 128;      // 8388608
static constexpr float kScaleLog2e = 0.11405506f;           // log2(e)/sqrt(160)
static constexpr unsigned kNegMask = 0xBF1Cu;               // BLADE_METRIC<0 bit i
static constexpr int kKBuf = 64 * 192;                      // 12288 f16 per K buffer
static constexpr int kVBuf = 160 * 64;                      // 10240 f16 per V buffer
static constexpr int kVArea = 2 * kKBuf;                    // V region base in combined LDS

// ---------------- pack K: f32 (mv|s) -> f16 [bh][key][160] ----------------
__global__ __launch_bounds__(256) void pack_k_kernel(const float* __restrict__ kmv,
                                                     const float* __restrict__ ks,
                                                     _Float16* __restrict__ Kf) {
  int t = blockIdx.x * 256 + threadIdx.x;  // 16B segment id
  const int total = BHn * Nn * 20;
  if (t >= total) return;
  int row = t / 20, s = t - row * 20;
  const float* src = (s < 16) ? (kmv + (size_t)row * 128 + s * 8)
                              : (ks + (size_t)row * 32 + (s - 16) * 8);
  float4 a = *(const float4*)src;
  float4 b = *(const float4*)(src + 4);
  f16x8 h;
  h[0] = (_Float16)a.x; h[1] = (_Float16)a.y; h[2] = (_Float16)a.z; h[3] = (_Float16)a.w;
  h[4] = (_Float16)b.x; h[5] = (_Float16)b.y; h[6] = (_Float16)b.z; h[7] = (_Float16)b.w;
  *(f16x8*)(Kf + (size_t)row * 160 + s * 8) = h;
}

// ---- pack V transposed + slot-permuted: f32 [bh][key][160] -> f16 [bh][d][1024] ----
// sigma(slot 8g+i) = 4g+i (i<4), 16+4g+(i-4) (i>=4): PV A-frag becomes lane-local.
__global__ __launch_bounds__(256) void pack_vt_kernel(const float* __restrict__ vmv,
                                                      const float* __restrict__ vs,
                                                      _Float16* __restrict__ Vt) {
  __shared__ _Float16 tile[160][72];
  const int bh = blockIdx.y;
  const int kt = blockIdx.x;  // 16 tiles of 64 keys
  const int tid = threadIdx.x;
  for (int s = tid; s < 64 * 40; s += 256) {
    int key = s / 40, p = s - key * 40;
    int row = bh * Nn + kt * 64 + key;
    const float* src = (p < 32) ? (vmv + (size_t)row * 128 + p * 4)
                                : (vs + (size_t)row * 32 + (p - 32) * 4);
    float4 v = *(const float4*)src;
    int d = p * 4;
    tile[d + 0][key] = (_Float16)v.x;
    tile[d + 1][key] = (_Float16)v.y;
    tile[d + 2][key] = (_Float16)v.z;
    tile[d + 3][key] = (_Float16)v.w;
  }
  __syncthreads();
  for (int s = tid; s < 160 * 8; s += 256) {
    int d = s >> 3, o = s & 7;
    int c32 = (o >> 2) * 32;
    int g4 = (o & 3) * 4;
    f16x4 lo = *(const f16x4*)&tile[d][c32 + g4];
    f16x4 hi = *(const f16x4*)&tile[d][c32 + 16 + g4];
    f16x8 h;
    h[0] = lo[0]; h[1] = lo[1]; h[2] = lo[2]; h[3] = lo[3];
    h[4] = hi[0]; h[5] = hi[1]; h[6] = hi[2]; h[7] = hi[3];
    *(f16x8*)(Vt + ((size_t)(bh * 160 + d)) * 1024 + kt * 64 + o * 8) = h;
  }
}

// --- flash attention: 8 waves x 32 rows, deferred-PV pipeline (T15), K dbuf + V tribuf ---
// grid: 256 blocks (XCD-swizzled -> (qb, bh)); 512 threads = 8 waves.
__global__ __launch_bounds__(512, 2) void geo_attn_kernel(const float* __restrict__ qmv,
                                                          const float* __restrict__ qs,
                                                          const _Float16* __restrict__ Kf,
                                                          const _Float16* __restrict__ Vt,
                                                          float* __restrict__ out) {
  __shared__ _Float16 kv[2 * kKBuf + 3 * kVBuf];  // 108 KB: K0,K1,V0,V1,V2

  // XCD swizzle: 256 blocks, XCD x gets bh 8x..8x+7 (all 4 q-blocks each)
  const int b = blockIdx.x;
  const int sw = (b & 7) * 32 + (b >> 3);
  const int qb = sw & 3;
  const int bh = sw >> 2;

  const int tid = threadIdx.x;
  const int w = tid >> 6;
  const int l = tid & 63;
  const int g = l >> 4;
  const int nn = l & 15;
  const int swz = (nn & 7) << 3;

  const _Float16* kg = Kf + (size_t)(bh * Nn) * 160;
  const _Float16* vg = Vt + (size_t)bh * 160 * Nn;

  // ---- staging geometry, hoisted: 2560 segs, 5/thread; ptr+stride+LDS-offset per seg ----
  const _Float16* sp[5];
  int sstp[5], ldsOff[5];
  bool segK[5];
#pragma unroll
  for (int i = 0; i < 5; ++i) {
    int sk = tid + 512 * i;
    if (sk < 1280) {  // K segment
      int key = sk / 20, p = sk - key * 20;
      sp[i] = kg + key * 160 + p * 8;
      sstp[i] = 64 * 160;
      ldsOff[i] = (key * 192 + p * 8) ^ ((key & 7) << 3);
      segK[i] = true;
    } else {          // V segment
      int s2 = sk - 1280;
      int d = s2 >> 3, cs = s2 & 7;
      sp[i] = vg + d * Nn + cs * 8;
      sstp[i] = 64;
      ldsOff[i] = (d * 64 + cs * 8) ^ ((d & 7) << 3);
      segK[i] = false;
    }
  }

  // ---- hoisted LDS read bases (XOR commutes with +3072*kb / +1024*j / buffer bases) ----
  int kbase[5], vboff[2];
#pragma unroll
  for (int c = 0; c < 5; ++c) kbase[c] = (nn * 192 + c * 32 + 8 * g) ^ swz;
#pragma unroll
  for (int ch = 0; ch < 2; ++ch) vboff[ch] = (nn * 64 + ch * 32 + 8 * g) ^ swz;

  // ---- Q fragments (B-frag): lane holds Q[q=nn(+16)][c*32+8g+i], metric*log2e/sqrt(d) folded ----
  f16x8 qf[2][5];
#pragma unroll
  for (int q2 = 0; q2 < 2; ++q2) {
    const size_t qbase = (size_t)(bh * Nn + qb * 256 + w * 32 + q2 * 16 + nn);
#pragma unroll
    for (int c = 0; c < 5; ++c) {
      const float* src = (c < 4) ? (qmv + qbase * 128 + c * 32 + 8 * g)
                                 : (qs + qbase * 32 + 8 * g);
      float4 a = *(const float4*)src;
      float4 bb = *(const float4*)(src + 4);
      float x[8] = {a.x, a.y, a.z, a.w, bb.x, bb.y, bb.z, bb.w};
#pragma unroll
      for (int i = 0; i < 8; ++i) {
        float v = x[i] * kScaleLog2e;
        if (c < 4) {
          int idx = ((g & 1) << 3) + i;
          v = ((kNegMask >> idx) & 1u) ? -v : v;
        }
        qf[q2][c][i] = (_Float16)v;
      }
    }
  }

  f32x4 acc[2][10];
#pragma unroll
  for (int q2 = 0; q2 < 2; ++q2)
#pragma unroll
    for (int j = 0; j < 10; ++j) acc[q2][j] = (f32x4){0.f, 0.f, 0.f, 0.f};
  float Ma = -3.0e38f, Mb = -3.0e38f, La = 0.f, Lb = 0.f;  // L: per-lane partials

  f32x4 sa[4], sb[4];
  f16x8 paf[2], pbf[2];   // P of the *previous* tile (pipeline register)
  f16x8 st[5];

  auto load_next = [&]() {
#pragma unroll
    for (int i = 0; i < 5; ++i) { st[i] = *(const f16x8*)sp[i]; sp[i] += sstp[i]; }
  };
  auto write_tile = [&](int kadd, int vadd) {
#pragma unroll
    for (int i = 0; i < 5; ++i)
      *(f16x8*)&kv[ldsOff[i] + (segK[i] ? kadd : vadd)] = st[i];
  };
  auto do_qk = [&](int kadd) {
#pragma unroll
    for (int kb = 0; kb < 4; ++kb) {
      sa[kb] = (f32x4){0.f, 0.f, 0.f, 0.f};
      sb[kb] = (f32x4){0.f, 0.f, 0.f, 0.f};
    }
#pragma unroll
    for (int c = 0; c < 5; ++c) {
      f16x8 kf[4];
#pragma unroll
      for (int kb = 0; kb < 4; ++kb)
        kf[kb] = *(const f16x8*)&kv[kadd + kbase[c] + 3072 * kb];
#pragma unroll
      for (int kb = 0; kb < 4; ++kb) {
        sa[kb] = __builtin_amdgcn_mfma_f32_16x16x32_f16(kf[kb], qf[0][c], sa[kb], 0, 0, 0);
        sb[kb] = __builtin_amdgcn_mfma_f32_16x16x32_f16(kf[kb], qf[1][c], sb[kb], 0, 0, 0);
      }
    }
  };
  auto do_pv = [&](int vadd) {
#pragma unroll
    for (int ch = 0; ch < 2; ++ch) {
#pragma unroll
      for (int j = 0; j < 10; ++j) {
        f16x8 vb = *(const f16x8*)&kv[vadd + vboff[ch] + 1024 * j];
        acc[0][j] = __builtin_amdgcn_mfma_f32_16x16x32_f16(paf[ch], vb, acc[0][j], 0, 0, 0);
        acc[1][j] = __builtin_amdgcn_mfma_f32_16x16x32_f16(pbf[ch], vb, acc[1][j], 0, 0, 0);
      }
    }
  };
  auto do_softmax = [&]() {
    float lma = fmaxf(fmaxf(fmaxf(fmaxf(sa[0][0], sa[0][1]), fmaxf(sa[0][2], sa[0][3])),
                            fmaxf(fmaxf(sa[1][0], sa[1][1]), fmaxf(sa[1][2], sa[1][3]))),
                      fmaxf(fmaxf(fmaxf(sa[2][0], sa[2][1]), fmaxf(sa[2][2], sa[2][3])),
                            fmaxf(fmaxf(sa[3][0], sa[3][1]), fmaxf(sa[3][2], sa[3][3]))));
    float lmb = fmaxf(fmaxf(fmaxf(fmaxf(sb[0][0], sb[0][1]), fmaxf(sb[0][2], sb[0][3])),
                            fmaxf(fmaxf(sb[1][0], sb[1][1]), fmaxf(sb[1][2], sb[1][3]))),
                      fmaxf(fmaxf(fmaxf(sb[2][0], sb[2][1]), fmaxf(sb[2][2], sb[2][3])),
                            fmaxf(fmaxf(sb[3][0], sb[3][1]), fmaxf(sb[3][2], sb[3][3]))));
    bool need = (lma - Ma > 8.f) || (lmb - Mb > 8.f);
    if (__any((int)need)) {   // rare: tile 0 + occasional
      float pma = fmaxf(lma, __shfl_xor(lma, 16));
      pma = fmaxf(pma, __shfl_xor(pma, 32));
      float pmb = fmaxf(lmb, __shfl_xor(lmb, 16));
      pmb = fmaxf(pmb, __shfl_xor(pmb, 32));
      float nMa = fmaxf(Ma, pma); float fsa = exp2f(Ma - nMa); Ma = nMa;
      float nMb = fmaxf(Mb, pmb); float fsb = exp2f(Mb - nMb); Mb = nMb;
      La *= fsa; Lb *= fsb;
      float fa[4], fb[4];
#pragma unroll
      for (int r = 0; r < 4; ++r) {
        fa[r] = __shfl(fsa, 4 * g + r, 16);
        fb[r] = __shfl(fsb, 4 * g + r, 16);
      }
#pragma unroll
      for (int j = 0; j < 10; ++j)
#pragma unroll
        for (int r = 0; r < 4; ++r) {
          acc[0][j][r] *= fa[r];
          acc[1][j][r] *= fb[r];
        }
    }
    float rsa = 0.f, rsb = 0.f;
#pragma unroll
    for (int kb = 0; kb < 4; ++kb) {
      const int ch = kb >> 1, off = (kb & 1) * 4;
#pragma unroll
      for (int r = 0; r < 4; ++r) {
        float pa_ = exp2f(sa[kb][r] - Ma);
        float pb_ = exp2f(sb[kb][r] - Mb);
        rsa += pa_; rsb += pb_;
        paf[ch][off + r] = (_Float16)pa_;
        pbf[ch][off + r] = (_Float16)pb_;
      }
    }
    La += rsa;
    Lb += rsb;
  };

  // ---- prologue: tile 0 staged, QK(0)+softmax(0); tile-1 loads in flight ----
  load_next();                    // tile 0
  write_tile(0, kVArea);          // -> K0, V0
  __syncthreads();
  load_next();                    // tile 1 (flies across QK+softmax)
  do_qk(0);
  do_softmax();                   // fills paf/pbf for PV(0)

  int kW = 1, vW = 1, vR = 0;
  for (int t = 1; t < 16; ++t) {
    write_tile(kW * kKBuf, kVArea + vW * kVBuf);   // tile t -> K[t&1], V[t%3]
    __syncthreads();                               // tile t visible; pv(t-2) done (prog order)
    if (t < 15) load_next();                       // tile t+1 issues now, lands next iter
    __builtin_amdgcn_s_setprio(1);
    do_qk(kW * kKBuf);                             // QK(t)   — 40 MFMA
    do_pv(kVArea + vR * kVBuf);                    // PV(t-1) — 40 MFMA, independent of QK(t)
    __builtin_amdgcn_s_setprio(0);
    do_softmax();                                  // softmax(t); VALU overlaps PV via scheduler
    kW ^= 1;
    vW = (vW == 2) ? 0 : vW + 1;
    vR = (vR == 2) ? 0 : vR + 1;
  }
  do_pv(kVArea + vR * kVBuf);                      // PV(15): vR == 15%3 == 0

  // ---- epilogue: reduce per-lane L partials, normalize, scatter ----
  La += __shfl_xor(La, 16); La += __shfl_xor(La, 32);
  Lb += __shfl_xor(Lb, 16); Lb += __shfl_xor(Lb, 32);
  float ria = 1.f / La, rib = 1.f / Lb;
  float ra[4], rb_[4];
#pragma unroll
  for (int r = 0; r < 4; ++r) {
    ra[r] = __shfl(ria, 4 * g + r, 16);
    rb_[r] = __shfl(rib, 4 * g + r, 16);
  }
  const int row0 = bh * Nn + qb * 256 + w * 32;
#pragma unroll
  for (int j = 0; j < 10; ++j) {
    const int d = 16 * j + nn;
#pragma unroll
    for (int r = 0; r < 4; ++r) {
      float v0 = acc[0][j][r] * ra[r];
      float v1 = acc[1][j][r] * rb_[r];
      const int r0 = row0 + 4 * g + r;
      const int r1 = row0 + 16 + 4 * g + r;
      if (d < 128) {
        out[(size_t)r0 * 128 + d] = v0;
        out[(size_t)r1 * 128 + d] = v1;
      } else {
        out[(size_t)kOutMvElems + (size_t)r0 * 32 + (d - 128)] = v0;
        out[(size_t)kOutMvElems + (size_t)r1 * 32 + (d - 128)] = v1;
      }
    }
  }
}

extern "C" void kernel_launch(void* const* d_in, const int* in_sizes, int n_in,
                              void* d_out, int out_size, void* d_ws, size_t ws_size,
                              hipStream_t stream) {
  const float* qmv = (const float*)d_in[0];
  const float* kmv = (const float*)d_in[1];
  const float* vmv = (const float*)d_in[2];
  const float* qs = (const float*)d_in[3];
  const float* ks = (const float*)d_in[4];
  const float* vs = (const float*)d_in[5];
  float* out = (float*)d_out;

  _Float16* Kf = (_Float16*)d_ws;                       // 64*1024*160 f16
  _Float16* Vt = Kf + (size_t)BHn * Nn * 160;           // 64*160*1024 f16 (sigma-permuted)

  pack_k_kernel<<<dim3((BHn * Nn * 20) / 256), dim3(256), 0, stream>>>(kmv, ks, Kf);
  pack_vt_kernel<<<dim3(16, BHn), dim3(256), 0, stream>>>(vmv, vs, Vt);
  geo_attn_kernel<<<dim3(256), dim3(512), 0, stream>>>(qmv, qs, Kf, Vt, out);
}